// Round 5
// baseline (431.011 us; speedup 1.0000x reference)
//
#include <hip/hip_runtime.h>
#include <hip/hip_bf16.h>
#include <math.h>

#define B_ 2
#define L_ 1024
#define D_ 1024
#define DI_ 2048
#define K_ 4
#define N_ 16
#define R_ 64
#define BL_ (B_ * L_)
#define EPS_ 1e-5f

// pad by 4 per 64 floats: keeps float4 alignment, breaks 64-stride bank conflicts
#define IDX4(l) ((l) + (((l) >> 6) << 2))

typedef __attribute__((ext_vector_type(8))) short short8;
typedef __attribute__((ext_vector_type(4))) float f32x4;

__device__ inline unsigned short f2bf(float f) {
    unsigned u = __float_as_uint(f);
    unsigned r = (u + 0x7fffu + ((u >> 16) & 1u)) >> 16;
    return (unsigned short)r;
}
__device__ inline float bf2f(unsigned short s) {
    return __uint_as_float(((unsigned)s) << 16);
}
__device__ inline float fast_silu(float z) {
    return z * __builtin_amdgcn_rcpf(1.f + __expf(-z));
}
__device__ inline void gl_lds16(const void* g, void* l) {
    __builtin_amdgcn_global_load_lds(
        (const __attribute__((address_space(1))) void*)g,
        (__attribute__((address_space(3))) void*)l, 16, 0, 0);
}

// DPP row_shr move (0-fill OOB); row = 16 lanes on CDNA
template <int CTRL>
__device__ inline float dpp_shr(float x) {
    return __int_as_float(__builtin_amdgcn_update_dpp(
        0, __float_as_int(x), CTRL, 0xf, 0xf, true));
}
// sum of the 16 lanes of a row; valid in lane (n==15) of each row
__device__ inline float row16_sum(float p) {
    p += dpp_shr<0x111>(p);   // row_shr:1
    p += dpp_shr<0x112>(p);   // row_shr:2
    p += dpp_shr<0x114>(p);   // row_shr:4
    p += dpp_shr<0x118>(p);   // row_shr:8
    return p;
}

// ---------------- LayerNorm -> bf16 output ----------------
__global__ void ln_kernel(const float* __restrict__ x, const float* __restrict__ w,
                          const float* __restrict__ b, unsigned short* __restrict__ hb) {
    int row = blockIdx.x;
    const float* xr = x + (size_t)row * D_;
    float4 v = ((const float4*)xr)[threadIdx.x];

    __shared__ float red[4];
    float s = v.x + v.y + v.z + v.w;
    for (int off = 1; off < 64; off <<= 1) s += __shfl_xor(s, off, 64);
    if ((threadIdx.x & 63) == 0) red[threadIdx.x >> 6] = s;
    __syncthreads();
    float mu = (red[0] + red[1] + red[2] + red[3]) * (1.0f / D_);
    __syncthreads();
    float cx = v.x - mu, cy = v.y - mu, cz = v.z - mu, cw = v.w - mu;
    float sq = cx*cx + cy*cy + cz*cz + cw*cw;
    for (int off = 1; off < 64; off <<= 1) sq += __shfl_xor(sq, off, 64);
    if ((threadIdx.x & 63) == 0) red[threadIdx.x >> 6] = sq;
    __syncthreads();
    float var = (red[0] + red[1] + red[2] + red[3]) * (1.0f / D_);
    float rstd = rsqrtf(var + EPS_);

    float4 wv = ((const float4*)w)[threadIdx.x];
    float4 bv = ((const float4*)b)[threadIdx.x];
    ushort4 o;
    o.x = f2bf(cx * rstd * wv.x + bv.x);
    o.y = f2bf(cy * rstd * wv.y + bv.y);
    o.z = f2bf(cz * rstd * wv.z + bv.z);
    o.w = f2bf(cw * rstd * wv.w + bv.w);
    ((ushort4*)(hb + (size_t)row * D_))[threadIdx.x] = o;
}

// ---------------- Transpose + cast: W (KxN f32) -> WT (NxK bf16) ----------------
__global__ void transpose_cast(const float* __restrict__ W, unsigned short* __restrict__ WT,
                               int K, int N) {
    __shared__ float tile[32][33];
    int k0 = blockIdx.y * 32, n0 = blockIdx.x * 32;
    int tr = threadIdx.x >> 5;
    int tc = threadIdx.x & 31;
#pragma unroll
    for (int i = 0; i < 4; ++i)
        tile[tr + i*8][tc] = W[(size_t)(k0 + tr + i*8) * N + n0 + tc];
    __syncthreads();
#pragma unroll
    for (int i = 0; i < 4; ++i)
        WT[(size_t)(n0 + tr + i*8) * K + k0 + tc] = f2bf(tile[tc][tr + i*8]);
}

// ---------------- MFMA bf16 GEMM: C(MxN) = A(MxK) * BT(NxK)^T ----------------
template <int BN, int MODE>
__global__ __launch_bounds__(256) void mfma_gemm_bt(
        const unsigned short* __restrict__ A,  int lda,
        const unsigned short* __restrict__ BT, int ldb,
        float* __restrict__ C, int ldc, int Kchunk) {
    constexpr int NT = BN / 32;
    __shared__ unsigned short As[128 * 32];
    __shared__ unsigned short Bs[BN * 32];

    int tid = threadIdx.x;
    int wave = tid >> 6, lane = tid & 63;
    int lane15 = lane & 15, quad = lane >> 4;
    int wr = wave >> 1, wc = wave & 1;

    int m0 = blockIdx.y * 128;
    int n0 = blockIdx.x * BN;
    int kbeg = blockIdx.z * Kchunk;
    int kend = kbeg + Kchunk;

    f32x4 acc[4][NT];
#pragma unroll
    for (int i = 0; i < 4; ++i)
#pragma unroll
        for (int j = 0; j < NT; ++j) acc[i][j] = (f32x4){0.f, 0.f, 0.f, 0.f};

    constexpr int ACALLS = 8;
    constexpr int BCALLS = BN * 4 / 64;

    for (int k0 = kbeg; k0 < kend; k0 += 32) {
        __syncthreads();
        for (int c = wave; c < ACALLS + BCALLS; c += 4) {
            if (c < ACALLS) {
                int cell = c * 64 + lane;
                int m = cell >> 2, s = cell & 3;
                int q = s ^ (m & 3) ^ ((m >> 2) & 3);
                gl_lds16(A + (size_t)(m0 + m) * lda + k0 + q * 8, &As[c * 512]);
            } else {
                int cell = (c - ACALLS) * 64 + lane;
                int n = cell >> 2, s = cell & 3;
                int q = s ^ (n & 3) ^ ((n >> 2) & 3);
                gl_lds16(BT + (size_t)(n0 + n) * ldb + k0 + q * 8, &Bs[(c - ACALLS) * 512]);
            }
        }
        __syncthreads();

        short8 af[4], bfr[NT];
#pragma unroll
        for (int i = 0; i < 4; ++i) {
            int m = wr * 64 + i * 16 + lane15;
            int s = quad ^ (m & 3) ^ ((m >> 2) & 3);
            af[i] = *(const short8*)&As[m * 32 + s * 8];
        }
#pragma unroll
        for (int j = 0; j < NT; ++j) {
            int n = wc * (NT * 16) + j * 16 + lane15;
            int s = quad ^ (n & 3) ^ ((n >> 2) & 3);
            bfr[j] = *(const short8*)&Bs[n * 32 + s * 8];
        }
#pragma unroll
        for (int i = 0; i < 4; ++i)
#pragma unroll
            for (int j = 0; j < NT; ++j)
                acc[i][j] = __builtin_amdgcn_mfma_f32_16x16x32_bf16(af[i], bfr[j], acc[i][j], 0, 0, 0);
    }

#pragma unroll
    for (int i = 0; i < 4; ++i) {
        int row = m0 + wr * 64 + i * 16 + quad * 4;
#pragma unroll
        for (int j = 0; j < NT; ++j) {
            int col = n0 + wc * (NT * 16) + j * 16 + lane15;
#pragma unroll
            for (int r = 0; r < 4; ++r) {
                float v = acc[i][j][r];
                size_t off = (size_t)(row + r) * ldc + col;
                if (MODE == 0) C[off] = v;
                else atomicAdd(&C[off], v);
            }
        }
    }
}

// ---------------- fp32 tiled GEMM (dt: K=64, softplus epilogue) ----------------
template <int EPI>
__global__ __launch_bounds__(256) void gemm_kernel(
        const float* __restrict__ A, int lda,
        const float* __restrict__ Bm, int ldb,
        float* __restrict__ C, int ldc,
        int M, int Nn, int Kk,
        const float* __restrict__ bias) {
    const int BK = 16;
    __shared__ float As[BK][64 + 4];
    __shared__ float Bs[BK][64];

    int tid = threadIdx.x;
    int m0 = blockIdx.y * 64;
    int n0 = blockIdx.x * 64;
    int ar = tid >> 2, ak = (tid & 3) << 2;
    int kb = tid >> 4, bc = (tid & 15) << 2;
    int ty = tid >> 4, tx = tid & 15;

    float acc[4][4] = {};
    for (int k0 = 0; k0 < Kk; k0 += BK) {
        const float* Ap = A + (size_t)(m0 + ar) * lda + (k0 + ak);
        float4 av = *(const float4*)Ap;
        As[ak + 0][ar] = av.x; As[ak + 1][ar] = av.y;
        As[ak + 2][ar] = av.z; As[ak + 3][ar] = av.w;

        const float* Bp = Bm + (size_t)(k0 + kb) * ldb + n0 + bc;
        float4 bv = *(const float4*)Bp;
        Bs[kb][bc + 0] = bv.x; Bs[kb][bc + 1] = bv.y;
        Bs[kb][bc + 2] = bv.z; Bs[kb][bc + 3] = bv.w;
        __syncthreads();
#pragma unroll
        for (int kk = 0; kk < BK; ++kk) {
            float a[4], bb[4];
#pragma unroll
            for (int i = 0; i < 4; ++i) a[i] = As[kk][ty * 4 + i];
#pragma unroll
            for (int j = 0; j < 4; ++j) bb[j] = Bs[kk][tx * 4 + j];
#pragma unroll
            for (int i = 0; i < 4; ++i)
#pragma unroll
                for (int j = 0; j < 4; ++j)
                    acc[i][j] = fmaf(a[i], bb[j], acc[i][j]);
        }
        __syncthreads();
    }
#pragma unroll
    for (int i = 0; i < 4; ++i) {
        int row = m0 + ty * 4 + i;
#pragma unroll
        for (int j = 0; j < 4; ++j) {
            int col = n0 + tx * 4 + j;
            float v = acc[i][j];
            if (EPI == 1) {
                v += bias[col];
                v = fmaxf(v, 0.f) + __logf(1.f + __expf(-fabsf(v)));
            }
            C[(size_t)row * ldc + col] = v;
        }
    }
}

// ---------------- Causal depthwise conv (K=4) + SiLU -> bf16 ----------------
__global__ void conv_silu_kernel(const float* __restrict__ xz, const float* __restrict__ cw,
                                 const float* __restrict__ cb, unsigned short* __restrict__ ub) {
    int idx = blockIdx.x * blockDim.x + threadIdx.x;
    int c = idx & (DI_ - 1);
    int bl = idx >> 11;
    int l = bl & (L_ - 1);
    float4 w4 = ((const float4*)cw)[c];
    float acc = cb[c];
    const float* base = xz + (size_t)bl * (2 * DI_) + c;
    if (l >= 3) {
        acc = fmaf(base[-(size_t)3 * 2 * DI_], w4.x, acc);
        acc = fmaf(base[-(size_t)2 * 2 * DI_], w4.y, acc);
        acc = fmaf(base[-(size_t)1 * 2 * DI_], w4.z, acc);
        acc = fmaf(base[0],                    w4.w, acc);
    } else {
        if (l >= 2) acc = fmaf(*(base - 2 * 2 * DI_), w4.y, acc);
        if (l >= 1) acc = fmaf(*(base - 1 * 2 * DI_), w4.z, acc);
        acc = fmaf(base[0], w4.w, acc);
    }
    ub[idx] = f2bf(fast_silu(acc));
}

// ---------------- Prep v2: (bl, c) -> (c, bl) streams for the scan ----------------
// dtT fp32; dtuT = bf16(dt*u); szdT = packed {lo: bf16(silu(z)), hi: bf16(u*D*silu(z))}
__global__ void prep_v2(const float* __restrict__ dt, const unsigned short* __restrict__ ub,
                        const float* __restrict__ xz, const float* __restrict__ Dp,
                        float* __restrict__ dtT, unsigned short* __restrict__ dtuT,
                        unsigned int* __restrict__ szdT) {
    __shared__ float t_dt[32][33];
    __shared__ unsigned short t_du[32][33];
    __shared__ unsigned int t_sd[32][33];
    int bl0 = blockIdx.y * 32, c0 = blockIdx.x * 32;
    int r = threadIdx.x >> 5;
    int col = threadIdx.x & 31;
    float dpv = Dp[c0 + col];
#pragma unroll
    for (int i = 0; i < 4; ++i) {
        int bl = bl0 + r + i*8;
        float d = dt[(size_t)bl * DI_ + c0 + col];
        float uu = bf2f(ub[(size_t)bl * DI_ + c0 + col]);
        float z = xz[(size_t)bl * (2 * DI_) + DI_ + c0 + col];
        float sz = fast_silu(z);
        t_dt[r + i*8][col] = d;
        t_du[r + i*8][col] = f2bf(d * uu);
        t_sd[r + i*8][col] = ((unsigned)f2bf(uu * dpv * sz) << 16) | (unsigned)f2bf(sz);
    }
    __syncthreads();
#pragma unroll
    for (int i = 0; i < 4; ++i) {
        int c = c0 + r + i*8;
        dtT [(size_t)c * BL_ + bl0 + col] = t_dt[col][r + i*8];
        dtuT[(size_t)c * BL_ + bl0 + col] = t_du[col][r + i*8];
        szdT[(size_t)c * BL_ + bl0 + col] = t_sd[col][r + i*8];
    }
}

// ---------------- B/C transpose: proj[:, R:R+32] -> bcT (32 x BL) ----------------
__global__ void bct_kernel(const float* __restrict__ proj, float* __restrict__ bcT) {
    __shared__ float t[32][33];
    int bl0 = blockIdx.x * 32;
    int r = threadIdx.x >> 5;
    int col = threadIdx.x & 31;
#pragma unroll
    for (int i = 0; i < 4; ++i)
        t[r + i*8][col] = proj[(size_t)(bl0 + r + i*8) * 96 + R_ + col];
    __syncthreads();
#pragma unroll
    for (int i = 0; i < 4; ++i)
        bcT[(size_t)(r + i*8) * BL_ + bl0 + col] = t[col][r + i*8];
}

// ---------------- Scan v3: reg-cached dA, DPP reduce, vectorized streams ----------------
__global__ __launch_bounds__(256) void scan_v3(
        const float* __restrict__ dtT, const unsigned short* __restrict__ dtuT,
        const unsigned int* __restrict__ szdT, const float* __restrict__ bcT,
        const float* __restrict__ A_log, unsigned short* __restrict__ yzT) {
    int bc = blockIdx.x;
    int b = bc >> 11;
    int c = bc & (DI_ - 1);
    int t = threadIdx.x;
    int chunk = t >> 4;
    int n = t & 15;

    __shared__ float sA[16][16];
    __shared__ float sB[16][16];
    __shared__ float ps[L_ + 64];

    const size_t tb = (size_t)c * BL_ + (size_t)b * L_;
    int l0 = chunk * 64;
    float A = -__expf(A_log[c * N_ + n]);

    const float*          dtp = dtT + tb + l0;
    const unsigned short* dup = dtuT + tb + l0;
    const float*          Bp  = bcT + (size_t)n * BL_ + (size_t)b * L_ + l0;
    const float*          Cp  = Bp + (size_t)16 * BL_;

    float dA[64];
    // Phase 1: chunk-local scan, cache dA in regs
    float a = 1.f, acc = 0.f;
#pragma unroll
    for (int q = 0; q < 16; ++q) {
        float4  d4 = *(const float4*)(dtp + q*4);
        ushort4 u4 = *(const ushort4*)(dup + q*4);
        float4  b4 = *(const float4*)(Bp + q*4);
        float e;
        e = __expf(d4.x * A); dA[q*4+0] = e; a *= e; acc = fmaf(e, acc, bf2f(u4.x) * b4.x);
        e = __expf(d4.y * A); dA[q*4+1] = e; a *= e; acc = fmaf(e, acc, bf2f(u4.y) * b4.y);
        e = __expf(d4.z * A); dA[q*4+2] = e; a *= e; acc = fmaf(e, acc, bf2f(u4.z) * b4.z);
        e = __expf(d4.w * A); dA[q*4+3] = e; a *= e; acc = fmaf(e, acc, bf2f(u4.w) * b4.w);
    }
    sA[chunk][n] = a;
    sB[chunk][n] = acc;
    __syncthreads();

    // Phase 2: serial combine across 16 chunks (one thread per n)
    if (t < 16) {
        float hc = 0.f;
#pragma unroll
        for (int j = 0; j < 16; ++j) {
            float aj = sA[j][t];
            float bj = sB[j][t];
            sB[j][t] = hc;
            hc = fmaf(aj, hc, bj);
        }
    }
    __syncthreads();
    float h = sB[chunk][n];

    // Phase 3: re-walk with reg dA; DPP row-sum; lane n==15 stores reduced p
    float* psb = &ps[IDX4(l0)];
#pragma unroll
    for (int q = 0; q < 16; ++q) {
        ushort4 u4 = *(const ushort4*)(dup + q*4);
        float4  b4 = *(const float4*)(Bp + q*4);
        float4  c4 = *(const float4*)(Cp + q*4);
        float p0, p1, p2, p3;
        h = fmaf(dA[q*4+0], h, bf2f(u4.x) * b4.x); p0 = row16_sum(h * c4.x);
        h = fmaf(dA[q*4+1], h, bf2f(u4.y) * b4.y); p1 = row16_sum(h * c4.y);
        h = fmaf(dA[q*4+2], h, bf2f(u4.z) * b4.z); p2 = row16_sum(h * c4.z);
        h = fmaf(dA[q*4+3], h, bf2f(u4.w) * b4.w); p3 = row16_sum(h * c4.w);
        if (n == 15) {
            *(float4*)&psb[q*4] = (float4){p0, p1, p2, p3};
        }
    }
    __syncthreads();

    // Epilogue: y = p * silu(z) + u*D*silu(z), vectorized
    {
        int l = t * 4;
        int il = IDX4(l);
        float4 p4 = *(const float4*)&ps[il];
        uint4 sd4 = *(const uint4*)(szdT + tb + l);
        ushort4 o;
        o.x = f2bf(p4.x * bf2f((unsigned short)(sd4.x & 0xffff)) + bf2f((unsigned short)(sd4.x >> 16)));
        o.y = f2bf(p4.y * bf2f((unsigned short)(sd4.y & 0xffff)) + bf2f((unsigned short)(sd4.y >> 16)));
        o.z = f2bf(p4.z * bf2f((unsigned short)(sd4.z & 0xffff)) + bf2f((unsigned short)(sd4.z >> 16)));
        o.w = f2bf(p4.w * bf2f((unsigned short)(sd4.w & 0xffff)) + bf2f((unsigned short)(sd4.w >> 16)));
        *(ushort4*)(yzT + tb + l) = o;
    }
}

// ---------------- Transpose back: yzT (DI x BL bf16) -> yz (BL x DI bf16) ----------------
__global__ void transpose_y(const unsigned short* __restrict__ yzT, unsigned short* __restrict__ yz) {
    __shared__ unsigned short t[32][33];
    int c0 = blockIdx.y * 32, bl0 = blockIdx.x * 32;
    int r = threadIdx.x >> 5;
    int col = threadIdx.x & 31;
#pragma unroll
    for (int i = 0; i < 4; ++i)
        t[r + i*8][col] = yzT[(size_t)(c0 + r + i*8) * BL_ + bl0 + col];
    __syncthreads();
#pragma unroll
    for (int i = 0; i < 4; ++i)
        yz[(size_t)(bl0 + r + i*8) * DI_ + c0 + col] = t[col][r + i*8];
}

extern "C" void kernel_launch(void* const* d_in, const int* in_sizes, int n_in,
                              void* d_out, int out_size, void* d_ws, size_t ws_size,
                              hipStream_t stream) {
    const float* x       = (const float*)d_in[0];
    const float* ln_w    = (const float*)d_in[1];
    const float* ln_b    = (const float*)d_in[2];
    const float* W_in    = (const float*)d_in[3];
    const float* conv_w  = (const float*)d_in[4];
    const float* conv_b  = (const float*)d_in[5];
    const float* W_x     = (const float*)d_in[6];
    const float* W_dt    = (const float*)d_in[7];
    const float* b_dt    = (const float*)d_in[8];
    const float* A_log   = (const float*)d_in[9];
    const float* D_param = (const float*)d_in[10];
    const float* W_out   = (const float*)d_in[11];
    float* out = (float*)d_out;

    uint8_t* p = (uint8_t*)d_ws;
    unsigned short* hb    = (unsigned short*)p;  p += (size_t)BL_ * D_ * 2;          // 4 MB   (dead after GEMM2)
    unsigned short* WinT  = (unsigned short*)p;  p += (size_t)4096 * 1024 * 2;       // 8 MB   (dead after GEMM2)
    float*          xz    = (float*)p;           p += (size_t)BL_ * 2 * DI_ * 4;     // 32 MB
    unsigned short* ub    = (unsigned short*)p;  p += (size_t)BL_ * DI_ * 2;         // 8 MB
    unsigned short* WxT   = (unsigned short*)p;  p += (size_t)96 * DI_ * 2;          // 0.375 MB
    float*          proj  = (float*)p;           p += (size_t)BL_ * 96 * 4;          // 0.75 MB
    float*          dt    = (float*)p;           p += (size_t)BL_ * DI_ * 4;         // 16 MB
    unsigned short* WoutT = (unsigned short*)p;  p += (size_t)1024 * DI_ * 2;        // 4 MB
    float*          dtT   = (float*)p;           p += (size_t)BL_ * DI_ * 4;         // 16 MB
    unsigned short* dtuT  = (unsigned short*)p;  p += (size_t)BL_ * DI_ * 2;         // 8 MB
    unsigned int*   szdT  = (unsigned int*)p;    p += (size_t)BL_ * DI_ * 4;         // 16 MB
    float*          bcT   = (float*)p;           p += (size_t)32 * BL_ * 4;          // 0.25 MB
    unsigned short* yzT   = (unsigned short*)p;  p += (size_t)BL_ * DI_ * 2;         // 8 MB
    // yzb aliases the dead hb+WinT region (needs 8 MB <= 12 MB; written after GEMM2 done)
    unsigned short* yzb   = (unsigned short*)d_ws;

    hipMemsetAsync(proj, 0, (size_t)BL_ * 96 * 4, stream);
    hipMemcpyAsync(out, x, (size_t)BL_ * D_ * 4, hipMemcpyDeviceToDevice, stream);

    transpose_cast<<<dim3(4096 / 32, 1024 / 32), 256, 0, stream>>>(W_in, WinT, 1024, 4096);
    transpose_cast<<<dim3(96 / 32, DI_ / 32), 256, 0, stream>>>(W_x, WxT, DI_, 96);
    transpose_cast<<<dim3(1024 / 32, DI_ / 32), 256, 0, stream>>>(W_out, WoutT, DI_, 1024);

    // 1. LayerNorm -> bf16
    ln_kernel<<<BL_, 256, 0, stream>>>(x, ln_w, ln_b, hb);

    // 2. xz = h @ W_in  (MFMA bf16)
    mfma_gemm_bt<128, 0><<<dim3(4096 / 128, BL_ / 128, 1), 256, 0, stream>>>(
        hb, 1024, WinT, 1024, xz, 4096, 1024);

    // 3. u = silu(conv(xi)) -> bf16
    conv_silu_kernel<<<(BL_ * DI_) / 256, 256, 0, stream>>>(xz, conv_w, conv_b, ub);

    // 4. proj += u @ W_x  (MFMA bf16, split-K=16 atomic)
    mfma_gemm_bt<96, 1><<<dim3(1, BL_ / 128, 16), 256, 0, stream>>>(
        ub, DI_, WxT, DI_, proj, 96, 128);

    // 5. dt = softplus(proj[:, :64] @ W_dt + b_dt)  (fp32, K=64)
    gemm_kernel<1><<<dim3(DI_ / 64, BL_ / 64), 256, 0, stream>>>(
        proj, 96, W_dt, DI_, dt, DI_, BL_, DI_, R_, b_dt);

    // 5b. transposed operand streams for the scan
    prep_v2<<<dim3(DI_ / 32, BL_ / 32), 256, 0, stream>>>(dt, ub, xz, D_param, dtT, dtuT, szdT);
    bct_kernel<<<BL_ / 32, 256, 0, stream>>>(proj, bcT);

    // 6. scan v3 -> yzT
    scan_v3<<<B_ * DI_, 256, 0, stream>>>(dtT, dtuT, szdT, bcT, A_log, yzT);

    // 6b. yzT -> row-major yzb
    transpose_y<<<dim3(BL_ / 32, DI_ / 32), 256, 0, stream>>>(yzT, yzb);

    // 7. out += yz @ W_out  (MFMA bf16, split-K=2 atomic onto residual)
    mfma_gemm_bt<128, 1><<<dim3(1024 / 128, BL_ / 128, 2), 256, 0, stream>>>(
        yzb, DI_, WoutT, DI_, out, 1024, 1024);
}

// Round 6
// 323.567 us; speedup vs baseline: 1.3321x; 1.3321x over previous
//
#include <hip/hip_runtime.h>
#include <hip/hip_bf16.h>
#include <math.h>

#define B_ 2
#define L_ 1024
#define D_ 1024
#define DI_ 2048
#define K_ 4
#define N_ 16
#define R_ 64
#define BL_ (B_ * L_)
#define EPS_ 1e-5f

// ps[] padding: +4 floats per 64 -> keeps float4 alignment, spreads banks
#define IDX4(l) ((l) + (((l) >> 6) << 2))

typedef __attribute__((ext_vector_type(8))) short short8;
typedef __attribute__((ext_vector_type(4))) float f32x4;

__device__ inline unsigned short f2bf(float f) {
    unsigned u = __float_as_uint(f);
    unsigned r = (u + 0x7fffu + ((u >> 16) & 1u)) >> 16;
    return (unsigned short)r;
}
__device__ inline float bf2f(unsigned short s) {
    return __uint_as_float(((unsigned)s) << 16);
}
__device__ inline float fast_silu(float z) {
    return z * __builtin_amdgcn_rcpf(1.f + __expf(-z));
}
__device__ inline void gl_lds16(const void* g, void* l) {
    __builtin_amdgcn_global_load_lds(
        (const __attribute__((address_space(1))) void*)g,
        (__attribute__((address_space(3))) void*)l, 16, 0, 0);
}

// DPP row_shr move (0-fill OOB); row = 16 lanes
template <int CTRL>
__device__ inline float dpp_shr(float x) {
    return __int_as_float(__builtin_amdgcn_update_dpp(
        0, __float_as_int(x), CTRL, 0xf, 0xf, true));
}
// sum of the 16 lanes of a row; valid in lane (n==15) of each row  [verified R5]
__device__ inline float row16_sum(float p) {
    p += dpp_shr<0x111>(p);
    p += dpp_shr<0x112>(p);
    p += dpp_shr<0x114>(p);
    p += dpp_shr<0x118>(p);
    return p;
}

// ---------------- LayerNorm -> bf16 output ----------------
__global__ void ln_kernel(const float* __restrict__ x, const float* __restrict__ w,
                          const float* __restrict__ b, unsigned short* __restrict__ hb) {
    int row = blockIdx.x;
    const float* xr = x + (size_t)row * D_;
    float4 v = ((const float4*)xr)[threadIdx.x];

    __shared__ float red[4];
    float s = v.x + v.y + v.z + v.w;
    for (int off = 1; off < 64; off <<= 1) s += __shfl_xor(s, off, 64);
    if ((threadIdx.x & 63) == 0) red[threadIdx.x >> 6] = s;
    __syncthreads();
    float mu = (red[0] + red[1] + red[2] + red[3]) * (1.0f / D_);
    __syncthreads();
    float cx = v.x - mu, cy = v.y - mu, cz = v.z - mu, cw = v.w - mu;
    float sq = cx*cx + cy*cy + cz*cz + cw*cw;
    for (int off = 1; off < 64; off <<= 1) sq += __shfl_xor(sq, off, 64);
    if ((threadIdx.x & 63) == 0) red[threadIdx.x >> 6] = sq;
    __syncthreads();
    float var = (red[0] + red[1] + red[2] + red[3]) * (1.0f / D_);
    float rstd = rsqrtf(var + EPS_);

    float4 wv = ((const float4*)w)[threadIdx.x];
    float4 bv = ((const float4*)b)[threadIdx.x];
    ushort4 o;
    o.x = f2bf(cx * rstd * wv.x + bv.x);
    o.y = f2bf(cy * rstd * wv.y + bv.y);
    o.z = f2bf(cz * rstd * wv.z + bv.z);
    o.w = f2bf(cw * rstd * wv.w + bv.w);
    ((ushort4*)(hb + (size_t)row * D_))[threadIdx.x] = o;
}

// ---------------- Transpose + cast: W (KxN f32) -> WT (NxK bf16) ----------------
__global__ void transpose_cast(const float* __restrict__ W, unsigned short* __restrict__ WT,
                               int K, int N) {
    __shared__ float tile[32][33];
    int k0 = blockIdx.y * 32, n0 = blockIdx.x * 32;
    int tr = threadIdx.x >> 5;
    int tc = threadIdx.x & 31;
#pragma unroll
    for (int i = 0; i < 4; ++i)
        tile[tr + i*8][tc] = W[(size_t)(k0 + tr + i*8) * N + n0 + tc];
    __syncthreads();
#pragma unroll
    for (int i = 0; i < 4; ++i)
        WT[(size_t)(n0 + tr + i*8) * K + k0 + tc] = f2bf(tile[tc][tr + i*8]);
}

// ---------------- MFMA bf16 GEMM: C(MxN) = A(MxK) * BT(NxK)^T ----------------
template <int BN, int MODE>
__global__ __launch_bounds__(256) void mfma_gemm_bt(
        const unsigned short* __restrict__ A,  int lda,
        const unsigned short* __restrict__ BT, int ldb,
        float* __restrict__ C, int ldc, int Kchunk) {
    constexpr int NT = BN / 32;
    __shared__ unsigned short As[128 * 32];
    __shared__ unsigned short Bs[BN * 32];

    int tid = threadIdx.x;
    int wave = tid >> 6, lane = tid & 63;
    int lane15 = lane & 15, quad = lane >> 4;
    int wr = wave >> 1, wc = wave & 1;

    int m0 = blockIdx.y * 128;
    int n0 = blockIdx.x * BN;
    int kbeg = blockIdx.z * Kchunk;
    int kend = kbeg + Kchunk;

    f32x4 acc[4][NT];
#pragma unroll
    for (int i = 0; i < 4; ++i)
#pragma unroll
        for (int j = 0; j < NT; ++j) acc[i][j] = (f32x4){0.f, 0.f, 0.f, 0.f};

    constexpr int ACALLS = 8;
    constexpr int BCALLS = BN * 4 / 64;

    for (int k0 = kbeg; k0 < kend; k0 += 32) {
        __syncthreads();
        for (int c = wave; c < ACALLS + BCALLS; c += 4) {
            if (c < ACALLS) {
                int cell = c * 64 + lane;
                int m = cell >> 2, s = cell & 3;
                int q = s ^ (m & 3) ^ ((m >> 2) & 3);
                gl_lds16(A + (size_t)(m0 + m) * lda + k0 + q * 8, &As[c * 512]);
            } else {
                int cell = (c - ACALLS) * 64 + lane;
                int n = cell >> 2, s = cell & 3;
                int q = s ^ (n & 3) ^ ((n >> 2) & 3);
                gl_lds16(BT + (size_t)(n0 + n) * ldb + k0 + q * 8, &Bs[(c - ACALLS) * 512]);
            }
        }
        __syncthreads();

        short8 af[4], bfr[NT];
#pragma unroll
        for (int i = 0; i < 4; ++i) {
            int m = wr * 64 + i * 16 + lane15;
            int s = quad ^ (m & 3) ^ ((m >> 2) & 3);
            af[i] = *(const short8*)&As[m * 32 + s * 8];
        }
#pragma unroll
        for (int j = 0; j < NT; ++j) {
            int n = wc * (NT * 16) + j * 16 + lane15;
            int s = quad ^ (n & 3) ^ ((n >> 2) & 3);
            bfr[j] = *(const short8*)&Bs[n * 32 + s * 8];
        }
#pragma unroll
        for (int i = 0; i < 4; ++i)
#pragma unroll
            for (int j = 0; j < NT; ++j)
                acc[i][j] = __builtin_amdgcn_mfma_f32_16x16x32_bf16(af[i], bfr[j], acc[i][j], 0, 0, 0);
    }

#pragma unroll
    for (int i = 0; i < 4; ++i) {
        int row = m0 + wr * 64 + i * 16 + quad * 4;
#pragma unroll
        for (int j = 0; j < NT; ++j) {
            int col = n0 + wc * (NT * 16) + j * 16 + lane15;
#pragma unroll
            for (int r = 0; r < 4; ++r) {
                float v = acc[i][j][r];
                size_t off = (size_t)(row + r) * ldc + col;
                if (MODE == 0) C[off] = v;
                else atomicAdd(&C[off], v);
            }
        }
    }
}

// ---------------- fp32 tiled GEMM (dt: K=64, softplus epilogue) ----------------
template <int EPI>
__global__ __launch_bounds__(256) void gemm_kernel(
        const float* __restrict__ A, int lda,
        const float* __restrict__ Bm, int ldb,
        float* __restrict__ C, int ldc,
        int M, int Nn, int Kk,
        const float* __restrict__ bias) {
    const int BK = 16;
    __shared__ float As[BK][64 + 4];
    __shared__ float Bs[BK][64];

    int tid = threadIdx.x;
    int m0 = blockIdx.y * 64;
    int n0 = blockIdx.x * 64;
    int ar = tid >> 2, ak = (tid & 3) << 2;
    int kb = tid >> 4, bc = (tid & 15) << 2;
    int ty = tid >> 4, tx = tid & 15;

    float acc[4][4] = {};
    for (int k0 = 0; k0 < Kk; k0 += BK) {
        const float* Ap = A + (size_t)(m0 + ar) * lda + (k0 + ak);
        float4 av = *(const float4*)Ap;
        As[ak + 0][ar] = av.x; As[ak + 1][ar] = av.y;
        As[ak + 2][ar] = av.z; As[ak + 3][ar] = av.w;

        const float* Bp = Bm + (size_t)(k0 + kb) * ldb + n0 + bc;
        float4 bv = *(const float4*)Bp;
        Bs[kb][bc + 0] = bv.x; Bs[kb][bc + 1] = bv.y;
        Bs[kb][bc + 2] = bv.z; Bs[kb][bc + 3] = bv.w;
        __syncthreads();
#pragma unroll
        for (int kk = 0; kk < BK; ++kk) {
            float a[4], bb[4];
#pragma unroll
            for (int i = 0; i < 4; ++i) a[i] = As[kk][ty * 4 + i];
#pragma unroll
            for (int j = 0; j < 4; ++j) bb[j] = Bs[kk][tx * 4 + j];
#pragma unroll
            for (int i = 0; i < 4; ++i)
#pragma unroll
                for (int j = 0; j < 4; ++j)
                    acc[i][j] = fmaf(a[i], bb[j], acc[i][j]);
        }
        __syncthreads();
    }
#pragma unroll
    for (int i = 0; i < 4; ++i) {
        int row = m0 + ty * 4 + i;
#pragma unroll
        for (int j = 0; j < 4; ++j) {
            int col = n0 + tx * 4 + j;
            float v = acc[i][j];
            if (EPI == 1) {
                v += bias[col];
                v = fmaxf(v, 0.f) + __logf(1.f + __expf(-fabsf(v)));
            }
            C[(size_t)row * ldc + col] = v;
        }
    }
}

// ---------------- Causal depthwise conv (K=4) + SiLU -> bf16 ----------------
__global__ void conv_silu_kernel(const float* __restrict__ xz, const float* __restrict__ cw,
                                 const float* __restrict__ cb, unsigned short* __restrict__ ub) {
    int idx = blockIdx.x * blockDim.x + threadIdx.x;
    int c = idx & (DI_ - 1);
    int bl = idx >> 11;
    int l = bl & (L_ - 1);
    float4 w4 = ((const float4*)cw)[c];
    float acc = cb[c];
    const float* base = xz + (size_t)bl * (2 * DI_) + c;
    if (l >= 3) {
        acc = fmaf(base[-(size_t)3 * 2 * DI_], w4.x, acc);
        acc = fmaf(base[-(size_t)2 * 2 * DI_], w4.y, acc);
        acc = fmaf(base[-(size_t)1 * 2 * DI_], w4.z, acc);
        acc = fmaf(base[0],                    w4.w, acc);
    } else {
        if (l >= 2) acc = fmaf(*(base - 2 * 2 * DI_), w4.y, acc);
        if (l >= 1) acc = fmaf(*(base - 1 * 2 * DI_), w4.z, acc);
        acc = fmaf(base[0], w4.w, acc);
    }
    ub[idx] = f2bf(fast_silu(acc));
}

// ---------------- Prep v3: (bl, c) -> (c, bl) packed streams ----------------
// dtduT[c*BL+bl] = {dt, dt*u} fp32; szdT = packed {lo: bf16(silu(z)), hi: bf16(u*D*silu(z))}
__global__ void prep_v3(const float* __restrict__ dt, const unsigned short* __restrict__ ub,
                        const float* __restrict__ xz, const float* __restrict__ Dp,
                        float2* __restrict__ dtduT, unsigned int* __restrict__ szdT) {
    __shared__ float t_dt[32][33];
    __shared__ float t_du[32][33];
    __shared__ unsigned int t_sd[32][33];
    int bl0 = blockIdx.y * 32, c0 = blockIdx.x * 32;
    int r = threadIdx.x >> 5;
    int col = threadIdx.x & 31;
    float dpv = Dp[c0 + col];
#pragma unroll
    for (int i = 0; i < 4; ++i) {
        int bl = bl0 + r + i*8;
        float d = dt[(size_t)bl * DI_ + c0 + col];
        float uu = bf2f(ub[(size_t)bl * DI_ + c0 + col]);
        float z = xz[(size_t)bl * (2 * DI_) + DI_ + c0 + col];
        float sz = fast_silu(z);
        t_dt[r + i*8][col] = d;
        t_du[r + i*8][col] = d * uu;
        t_sd[r + i*8][col] = ((unsigned)f2bf(uu * dpv * sz) << 16) | (unsigned)f2bf(sz);
    }
    __syncthreads();
#pragma unroll
    for (int i = 0; i < 4; ++i) {
        int c = c0 + r + i*8;
        dtduT[(size_t)c * BL_ + bl0 + col] = make_float2(t_dt[col][r + i*8], t_du[col][r + i*8]);
        szdT [(size_t)c * BL_ + bl0 + col] = t_sd[col][r + i*8];
    }
}

// ---------------- B/C interleave: proj[:, R:R+32] -> bcti[bl][n] = {B_n, C_n} ----------------
__global__ void bct2_kernel(const float* __restrict__ proj, float2* __restrict__ bcti) {
    int t = threadIdx.x;
    int bl = blockIdx.x * 16 + (t >> 4);
    int n = t & 15;
    float Bv = proj[(size_t)bl * 96 + R_ + n];
    float Cv = proj[(size_t)bl * 96 + R_ + N_ + n];
    bcti[(size_t)bl * 16 + n] = make_float2(Bv, Cv);
}

// ---------------- Scan v4: LDS-staged packed streams, DPP reduce, 2-walk ----------------
__global__ __launch_bounds__(256) void scan_v4(
        const float2* __restrict__ dtduT, const unsigned int* __restrict__ szdT,
        const float2* __restrict__ bcti, const float* __restrict__ A_log,
        unsigned short* __restrict__ yzT) {
    int bc = blockIdx.x;
    int b = bc >> 11;
    int c = bc & (DI_ - 1);
    int t = threadIdx.x;
    int chunk = t >> 4;
    int n = t & 15;

    __shared__ float dd[(L_ + 32) * 2];   // {dt, dtu} per l; +2 float2 pad per 64
    __shared__ float sA[16][16];
    __shared__ float sB[16][16];
    __shared__ float ps[L_ + 64];

    const size_t tb = (size_t)c * BL_ + (size_t)b * L_;

    {   // stage: thread t covers l = 4t..4t+3 (8 floats), coalesced, b128 LDS writes
        int l = t * 4;
        const float4* g = (const float4*)(dtduT + tb + l);
        float4 a0 = g[0], a1 = g[1];
        int il2 = l + ((l >> 6) << 1);
        *(float4*)&dd[il2 * 2]     = a0;
        *(float4*)&dd[il2 * 2 + 4] = a1;
    }
    __syncthreads();

    float A = -__expf(A_log[c * N_ + n]);
    int l0 = chunk * 64;
    const float* ddp = &dd[(l0 + 2 * chunk) * 2];            // contiguous 128 floats
    const float* bcf = (const float*)(bcti + ((size_t)b * L_ + l0) * 16 + n);

    // Phase 1: chunk-local scan
    float a = 1.f, acc = 0.f;
#pragma unroll
    for (int q = 0; q < 16; ++q) {
        float4 d0 = *(const float4*)(ddp + q * 8);           // {dt0,du0,dt1,du1}
        float4 d1 = *(const float4*)(ddp + q * 8 + 4);       // {dt2,du2,dt3,du3}
        float b0 = bcf[(q*4 + 0) * 32];
        float b1 = bcf[(q*4 + 1) * 32];
        float b2 = bcf[(q*4 + 2) * 32];
        float b3 = bcf[(q*4 + 3) * 32];
        float e;
        e = __expf(d0.x * A); a *= e; acc = fmaf(e, acc, d0.y * b0);
        e = __expf(d0.z * A); a *= e; acc = fmaf(e, acc, d0.w * b1);
        e = __expf(d1.x * A); a *= e; acc = fmaf(e, acc, d1.y * b2);
        e = __expf(d1.z * A); a *= e; acc = fmaf(e, acc, d1.w * b3);
    }
    sA[chunk][n] = a;
    sB[chunk][n] = acc;
    __syncthreads();

    // Phase 2: serial combine across 16 chunks (one thread per n)
    if (t < 16) {
        float hc = 0.f;
#pragma unroll
        for (int j = 0; j < 16; ++j) {
            float aj = sA[j][t];
            float bj = sB[j][t];
            sB[j][t] = hc;
            hc = fmaf(aj, hc, bj);
        }
    }
    __syncthreads();
    float h = sB[chunk][n];

    // Phase 3: re-walk with carry-in; DPP row-sum lands in lane n==15
    float* psb = &ps[IDX4(l0)];
    const float2* bcp = bcti + ((size_t)b * L_ + l0) * 16 + n;
#pragma unroll
    for (int q = 0; q < 16; ++q) {
        float4 d0 = *(const float4*)(ddp + q * 8);
        float4 d1 = *(const float4*)(ddp + q * 8 + 4);
        float2 bc0 = bcp[(q*4 + 0) * 16];
        float2 bc1 = bcp[(q*4 + 1) * 16];
        float2 bc2 = bcp[(q*4 + 2) * 16];
        float2 bc3 = bcp[(q*4 + 3) * 16];
        float e, p0, p1, p2, p3;
        e = __expf(d0.x * A); h = fmaf(e, h, d0.y * bc0.x); p0 = row16_sum(h * bc0.y);
        e = __expf(d0.z * A); h = fmaf(e, h, d0.w * bc1.x); p1 = row16_sum(h * bc1.y);
        e = __expf(d1.x * A); h = fmaf(e, h, d1.y * bc2.x); p2 = row16_sum(h * bc2.y);
        e = __expf(d1.z * A); h = fmaf(e, h, d1.w * bc3.x); p3 = row16_sum(h * bc3.y);
        if (n == 15) *(float4*)&psb[q * 4] = (float4){p0, p1, p2, p3};
    }
    __syncthreads();

    // Epilogue: y = p * silu(z) + u*D*silu(z), vectorized coalesced
    {
        int l = t * 4;
        int il = IDX4(l);
        float4 p4 = *(const float4*)&ps[il];
        uint4 sd4 = *(const uint4*)(szdT + tb + l);
        ushort4 o;
        o.x = f2bf(p4.x * bf2f((unsigned short)(sd4.x & 0xffff)) + bf2f((unsigned short)(sd4.x >> 16)));
        o.y = f2bf(p4.y * bf2f((unsigned short)(sd4.y & 0xffff)) + bf2f((unsigned short)(sd4.y >> 16)));
        o.z = f2bf(p4.z * bf2f((unsigned short)(sd4.z & 0xffff)) + bf2f((unsigned short)(sd4.z >> 16)));
        o.w = f2bf(p4.w * bf2f((unsigned short)(sd4.w & 0xffff)) + bf2f((unsigned short)(sd4.w >> 16)));
        *(ushort4*)(yzT + tb + l) = o;
    }
}

// ---------------- Transpose back: yzT (DI x BL bf16) -> yz (BL x DI bf16) ----------------
__global__ void transpose_y(const unsigned short* __restrict__ yzT, unsigned short* __restrict__ yz) {
    __shared__ unsigned short t[32][33];
    int c0 = blockIdx.y * 32, bl0 = blockIdx.x * 32;
    int r = threadIdx.x >> 5;
    int col = threadIdx.x & 31;
#pragma unroll
    for (int i = 0; i < 4; ++i)
        t[r + i*8][col] = yzT[(size_t)(c0 + r + i*8) * BL_ + bl0 + col];
    __syncthreads();
#pragma unroll
    for (int i = 0; i < 4; ++i)
        yz[(size_t)(bl0 + r + i*8) * DI_ + c0 + col] = t[col][r + i*8];
}

extern "C" void kernel_launch(void* const* d_in, const int* in_sizes, int n_in,
                              void* d_out, int out_size, void* d_ws, size_t ws_size,
                              hipStream_t stream) {
    const float* x       = (const float*)d_in[0];
    const float* ln_w    = (const float*)d_in[1];
    const float* ln_b    = (const float*)d_in[2];
    const float* W_in    = (const float*)d_in[3];
    const float* conv_w  = (const float*)d_in[4];
    const float* conv_b  = (const float*)d_in[5];
    const float* W_x     = (const float*)d_in[6];
    const float* W_dt    = (const float*)d_in[7];
    const float* b_dt    = (const float*)d_in[8];
    const float* A_log   = (const float*)d_in[9];
    const float* D_param = (const float*)d_in[10];
    const float* W_out   = (const float*)d_in[11];
    float* out = (float*)d_out;

    uint8_t* p = (uint8_t*)d_ws;
    unsigned short* hb    = (unsigned short*)p;  p += (size_t)BL_ * D_ * 2;          // 4 MB  (dead after GEMM2)
    unsigned short* WinT  = (unsigned short*)p;  p += (size_t)4096 * 1024 * 2;       // 8 MB  (dead after GEMM2)
    float*          xz    = (float*)p;           p += (size_t)BL_ * 2 * DI_ * 4;     // 32 MB
    unsigned short* ub    = (unsigned short*)p;  p += (size_t)BL_ * DI_ * 2;         // 8 MB
    unsigned short* WxT   = (unsigned short*)p;  p += (size_t)96 * DI_ * 2;          // 0.375 MB
    float*          proj  = (float*)p;           p += (size_t)BL_ * 96 * 4;          // 0.75 MB
    float*          dt    = (float*)p;           p += (size_t)BL_ * DI_ * 4;         // 16 MB
    unsigned short* WoutT = (unsigned short*)p;  p += (size_t)1024 * DI_ * 2;        // 4 MB
    float2*         dtduT = (float2*)p;          p += (size_t)BL_ * DI_ * 8;         // 32 MB
    unsigned int*   szdT  = (unsigned int*)p;    p += (size_t)BL_ * DI_ * 4;         // 16 MB
    float2*         bcti  = (float2*)p;          p += (size_t)BL_ * 16 * 8;          // 0.25 MB
    unsigned short* yzT   = (unsigned short*)p;  p += (size_t)BL_ * DI_ * 2;         // 8 MB
    // yzb aliases the dead hb+WinT region (8 MB <= 12 MB; written after GEMM2 done)
    unsigned short* yzb   = (unsigned short*)d_ws;

    hipMemsetAsync(proj, 0, (size_t)BL_ * 96 * 4, stream);
    hipMemcpyAsync(out, x, (size_t)BL_ * D_ * 4, hipMemcpyDeviceToDevice, stream);

    transpose_cast<<<dim3(4096 / 32, 1024 / 32), 256, 0, stream>>>(W_in, WinT, 1024, 4096);
    transpose_cast<<<dim3(96 / 32, DI_ / 32), 256, 0, stream>>>(W_x, WxT, DI_, 96);
    transpose_cast<<<dim3(1024 / 32, DI_ / 32), 256, 0, stream>>>(W_out, WoutT, DI_, 1024);

    // 1. LayerNorm -> bf16
    ln_kernel<<<BL_, 256, 0, stream>>>(x, ln_w, ln_b, hb);

    // 2. xz = h @ W_in  (MFMA bf16)
    mfma_gemm_bt<128, 0><<<dim3(4096 / 128, BL_ / 128, 1), 256, 0, stream>>>(
        hb, 1024, WinT, 1024, xz, 4096, 1024);

    // 3. u = silu(conv(xi)) -> bf16
    conv_silu_kernel<<<(BL_ * DI_) / 256, 256, 0, stream>>>(xz, conv_w, conv_b, ub);

    // 4. proj += u @ W_x  (MFMA bf16, split-K=16 atomic)
    mfma_gemm_bt<96, 1><<<dim3(1, BL_ / 128, 16), 256, 0, stream>>>(
        ub, DI_, WxT, DI_, proj, 96, 128);

    // 5. dt = softplus(proj[:, :64] @ W_dt + b_dt)  (fp32, K=64)
    gemm_kernel<1><<<dim3(DI_ / 64, BL_ / 64), 256, 0, stream>>>(
        proj, 96, W_dt, DI_, dt, DI_, BL_, DI_, R_, b_dt);

    // 5b. packed transposed operand streams for the scan
    prep_v3<<<dim3(DI_ / 32, BL_ / 32), 256, 0, stream>>>(dt, ub, xz, D_param, dtduT, szdT);
    bct2_kernel<<<BL_ / 16, 256, 0, stream>>>(proj, bcti);

    // 6. scan v4 -> yzT
    scan_v4<<<B_ * DI_, 256, 0, stream>>>(dtduT, szdT, bcti, A_log, yzT);

    // 6b. yzT -> row-major yzb
    transpose_y<<<dim3(BL_ / 32, DI_ / 32), 256, 0, stream>>>(yzT, yzb);

    // 7. out += yz @ W_out  (MFMA bf16, split-K=2 atomic onto residual)
    mfma_gemm_bt<128, 1><<<dim3(1024 / 128, BL_ / 128, 2), 256, 0, stream>>>(
        yzb, DI_, WoutT, DI_, out, 1024, 1024);
}

// Round 7
// 286.717 us; speedup vs baseline: 1.5033x; 1.1285x over previous
//
#include <hip/hip_runtime.h>
#include <hip/hip_bf16.h>
#include <math.h>

#define B_ 2
#define L_ 1024
#define D_ 1024
#define DI_ 2048
#define K_ 4
#define N_ 16
#define R_ 64
#define BL_ (B_ * L_)
#define EPS_ 1e-5f

#define IDX4(l) ((l) + (((l) >> 6) << 2))

typedef __attribute__((ext_vector_type(8))) short short8;
typedef __attribute__((ext_vector_type(4))) float f32x4;

__device__ inline unsigned short f2bf(float f) {
    unsigned u = __float_as_uint(f);
    unsigned r = (u + 0x7fffu + ((u >> 16) & 1u)) >> 16;
    return (unsigned short)r;
}
__device__ inline float bf2f(unsigned short s) {
    return __uint_as_float(((unsigned)s) << 16);
}
__device__ inline float fast_silu(float z) {
    return z * __builtin_amdgcn_rcpf(1.f + __expf(-z));
}
__device__ inline void gl_lds16(const void* g, void* l) {
    __builtin_amdgcn_global_load_lds(
        (const __attribute__((address_space(1))) void*)g,
        (__attribute__((address_space(3))) void*)l, 16, 0, 0);
}

// DPP row_shr; row = 16 lanes. Sum lands in lane (n==15) of each 16-lane row. [verified R5/R6]
template <int CTRL>
__device__ inline float dpp_shr(float x) {
    return __int_as_float(__builtin_amdgcn_update_dpp(
        0, __float_as_int(x), CTRL, 0xf, 0xf, true));
}
__device__ inline float row16_sum(float p) {
    p += dpp_shr<0x111>(p);
    p += dpp_shr<0x112>(p);
    p += dpp_shr<0x114>(p);
    p += dpp_shr<0x118>(p);
    return p;
}

// ---------------- LayerNorm -> bf16 ----------------
__global__ void ln_kernel(const float* __restrict__ x, const float* __restrict__ w,
                          const float* __restrict__ b, unsigned short* __restrict__ hb) {
    int row = blockIdx.x;
    const float* xr = x + (size_t)row * D_;
    float4 v = ((const float4*)xr)[threadIdx.x];

    __shared__ float red[4];
    float s = v.x + v.y + v.z + v.w;
    for (int off = 1; off < 64; off <<= 1) s += __shfl_xor(s, off, 64);
    if ((threadIdx.x & 63) == 0) red[threadIdx.x >> 6] = s;
    __syncthreads();
    float mu = (red[0] + red[1] + red[2] + red[3]) * (1.0f / D_);
    __syncthreads();
    float cx = v.x - mu, cy = v.y - mu, cz = v.z - mu, cw = v.w - mu;
    float sq = cx*cx + cy*cy + cz*cz + cw*cw;
    for (int off = 1; off < 64; off <<= 1) sq += __shfl_xor(sq, off, 64);
    if ((threadIdx.x & 63) == 0) red[threadIdx.x >> 6] = sq;
    __syncthreads();
    float var = (red[0] + red[1] + red[2] + red[3]) * (1.0f / D_);
    float rstd = rsqrtf(var + EPS_);

    float4 wv = ((const float4*)w)[threadIdx.x];
    float4 bv = ((const float4*)b)[threadIdx.x];
    ushort4 o;
    o.x = f2bf(cx * rstd * wv.x + bv.x);
    o.y = f2bf(cy * rstd * wv.y + bv.y);
    o.z = f2bf(cz * rstd * wv.z + bv.z);
    o.w = f2bf(cw * rstd * wv.w + bv.w);
    ((ushort4*)(hb + (size_t)row * D_))[threadIdx.x] = o;
}

// ---------------- Merged transpose+cast of all three weights ----------------
__global__ void transpose_cast_all(const float* __restrict__ W_in, const float* __restrict__ W_x,
                                   const float* __restrict__ W_out,
                                   unsigned short* __restrict__ WinT, unsigned short* __restrict__ WxT,
                                   unsigned short* __restrict__ WoutT) {
    int bid = blockIdx.x;
    const float* W; unsigned short* WT; int K, N, bx, by;
    if (bid < 4096)      { W = W_in;  WT = WinT;  K = 1024; N = 4096; bx = bid & 127; by = bid >> 7; }
    else if (bid < 4288) { int id = bid - 4096; W = W_x;  WT = WxT;  K = DI_; N = 96;   bx = id % 3;  by = id / 3; }
    else                 { int id = bid - 4288; W = W_out; WT = WoutT; K = DI_; N = 1024; bx = id & 31; by = id >> 5; }
    __shared__ float tile[32][33];
    int k0 = by * 32, n0 = bx * 32;
    int tr = threadIdx.x >> 5;
    int tc = threadIdx.x & 31;
#pragma unroll
    for (int i = 0; i < 4; ++i)
        tile[tr + i*8][tc] = W[(size_t)(k0 + tr + i*8) * N + n0 + tc];
    __syncthreads();
#pragma unroll
    for (int i = 0; i < 4; ++i)
        WT[(size_t)(n0 + tr + i*8) * K + k0 + tc] = f2bf(tile[tc][tr + i*8]);
}

// ---------------- MFMA bf16 GEMM: C(MxN) = A(MxK) * BT(NxK)^T ----------------
// MODE 0: plain store. MODE 1: atomicAdd. MODE 3: xz-split (col<DI -> xi fp32; col>=DI -> silu bf16)
template <int BN, int MODE>
__global__ __launch_bounds__(256) void mfma_gemm_bt(
        const unsigned short* __restrict__ A,  int lda,
        const unsigned short* __restrict__ BT, int ldb,
        float* __restrict__ C, int ldc, int Kchunk,
        float* __restrict__ xi, unsigned short* __restrict__ sz) {
    constexpr int NT = BN / 32;
    __shared__ unsigned short As[128 * 32];
    __shared__ unsigned short Bs[BN * 32];

    int tid = threadIdx.x;
    int wave = tid >> 6, lane = tid & 63;
    int lane15 = lane & 15, quad = lane >> 4;
    int wr = wave >> 1, wc = wave & 1;

    int m0 = blockIdx.y * 128;
    int n0 = blockIdx.x * BN;
    int kbeg = blockIdx.z * Kchunk;
    int kend = kbeg + Kchunk;

    f32x4 acc[4][NT];
#pragma unroll
    for (int i = 0; i < 4; ++i)
#pragma unroll
        for (int j = 0; j < NT; ++j) acc[i][j] = (f32x4){0.f, 0.f, 0.f, 0.f};

    constexpr int ACALLS = 8;
    constexpr int BCALLS = BN * 4 / 64;

    for (int k0 = kbeg; k0 < kend; k0 += 32) {
        __syncthreads();
        for (int c = wave; c < ACALLS + BCALLS; c += 4) {
            if (c < ACALLS) {
                int cell = c * 64 + lane;
                int m = cell >> 2, s = cell & 3;
                int q = s ^ (m & 3) ^ ((m >> 2) & 3);
                gl_lds16(A + (size_t)(m0 + m) * lda + k0 + q * 8, &As[c * 512]);
            } else {
                int cell = (c - ACALLS) * 64 + lane;
                int n = cell >> 2, s = cell & 3;
                int q = s ^ (n & 3) ^ ((n >> 2) & 3);
                gl_lds16(BT + (size_t)(n0 + n) * ldb + k0 + q * 8, &Bs[(c - ACALLS) * 512]);
            }
        }
        __syncthreads();

        short8 af[4], bfr[NT];
#pragma unroll
        for (int i = 0; i < 4; ++i) {
            int m = wr * 64 + i * 16 + lane15;
            int s = quad ^ (m & 3) ^ ((m >> 2) & 3);
            af[i] = *(const short8*)&As[m * 32 + s * 8];
        }
#pragma unroll
        for (int j = 0; j < NT; ++j) {
            int n = wc * (NT * 16) + j * 16 + lane15;
            int s = quad ^ (n & 3) ^ ((n >> 2) & 3);
            bfr[j] = *(const short8*)&Bs[n * 32 + s * 8];
        }
#pragma unroll
        for (int i = 0; i < 4; ++i)
#pragma unroll
            for (int j = 0; j < NT; ++j)
                acc[i][j] = __builtin_amdgcn_mfma_f32_16x16x32_bf16(af[i], bfr[j], acc[i][j], 0, 0, 0);
    }

#pragma unroll
    for (int i = 0; i < 4; ++i) {
        int row = m0 + wr * 64 + i * 16 + quad * 4;
#pragma unroll
        for (int j = 0; j < NT; ++j) {
            int col = n0 + wc * (NT * 16) + j * 16 + lane15;
#pragma unroll
            for (int r = 0; r < 4; ++r) {
                float v = acc[i][j][r];
                int rr = row + r;
                if (MODE == 0) {
                    C[(size_t)rr * ldc + col] = v;
                } else if (MODE == 1) {
                    atomicAdd(&C[(size_t)rr * ldc + col], v);
                } else {   // MODE 3
                    if (col < DI_) xi[(size_t)rr * DI_ + col] = v;
                    else           sz[(size_t)rr * DI_ + (col - DI_)] = f2bf(fast_silu(v));
                }
            }
        }
    }
}

// ---------------- Causal depthwise conv (K=4) + SiLU -> bf16 ----------------
__global__ void conv_silu_kernel(const float* __restrict__ xi, const float* __restrict__ cw,
                                 const float* __restrict__ cb, unsigned short* __restrict__ ub) {
    int idx = blockIdx.x * blockDim.x + threadIdx.x;
    int c = idx & (DI_ - 1);
    int bl = idx >> 11;
    int l = bl & (L_ - 1);
    float4 w4 = ((const float4*)cw)[c];
    float acc = cb[c];
    const float* base = xi + (size_t)bl * DI_ + c;
    if (l >= 3) {
        acc = fmaf(base[-(size_t)3 * DI_], w4.x, acc);
        acc = fmaf(base[-(size_t)2 * DI_], w4.y, acc);
        acc = fmaf(base[-(size_t)1 * DI_], w4.z, acc);
        acc = fmaf(base[0],                w4.w, acc);
    } else {
        if (l >= 2) acc = fmaf(*(base - 2 * DI_), w4.y, acc);
        if (l >= 1) acc = fmaf(*(base - 1 * DI_), w4.z, acc);
        acc = fmaf(base[0], w4.w, acc);
    }
    ub[idx] = f2bf(fast_silu(acc));
}

// ---------------- Fused dt-GEMM + softplus + pack + transpose ----------------
// dt[bl][c] = softplus(proj[bl,:64] @ W_dt[:,c] + b_dt[c]); writes
// dtduT[c*BL+bl] = {dt, dt*u} fp32 and szdT[c*BL+bl] = {hi: bf16(u*D*sz), lo: bf16(sz)}
__global__ __launch_bounds__(256) void dtprep(
        const float* __restrict__ proj, const float* __restrict__ W_dt,
        const float* __restrict__ b_dt, const unsigned short* __restrict__ ub,
        const unsigned short* __restrict__ szb, const float* __restrict__ Dp,
        float2* __restrict__ dtduT, unsigned int* __restrict__ szdT) {
    __shared__ alignas(16) unsigned char smem[64 * 65 * 8];   // 33280 B, multi-purpose
    float (*As)[68] = reinterpret_cast<float(*)[68]>(smem);           // 16x68x4 = 4352
    float (*Bs)[64] = reinterpret_cast<float(*)[64]>(smem + 4352);    // 16x64x4 = 4096
    float2 (*T2)[65] = reinterpret_cast<float2(*)[65]>(smem);         // 64x65x8
    unsigned int (*TU)[65] = reinterpret_cast<unsigned int(*)[65]>(smem); // 64x65x4

    int tid = threadIdx.x;
    int n0 = blockIdx.x * 64;   // c tile
    int m0 = blockIdx.y * 64;   // bl tile
    int ar = tid >> 2, ak = (tid & 3) << 2;
    int kb = tid >> 4, bc = (tid & 15) << 2;
    int ty = tid >> 4, tx = tid & 15;

    float acc[4][4] = {};
#pragma unroll
    for (int k0 = 0; k0 < R_; k0 += 16) {
        float4 av = *(const float4*)&proj[(size_t)(m0 + ar) * 96 + k0 + ak];
        As[ak + 0][ar] = av.x; As[ak + 1][ar] = av.y;
        As[ak + 2][ar] = av.z; As[ak + 3][ar] = av.w;
        float4 bv = *(const float4*)&W_dt[(size_t)(k0 + kb) * DI_ + n0 + bc];
        Bs[kb][bc + 0] = bv.x; Bs[kb][bc + 1] = bv.y;
        Bs[kb][bc + 2] = bv.z; Bs[kb][bc + 3] = bv.w;
        __syncthreads();
#pragma unroll
        for (int kk = 0; kk < 16; ++kk) {
            float a[4], bb[4];
#pragma unroll
            for (int i = 0; i < 4; ++i) a[i] = As[kk][ty * 4 + i];
#pragma unroll
            for (int j = 0; j < 4; ++j) bb[j] = Bs[kk][tx * 4 + j];
#pragma unroll
            for (int i = 0; i < 4; ++i)
#pragma unroll
                for (int j = 0; j < 4; ++j)
                    acc[i][j] = fmaf(a[i], bb[j], acc[i][j]);
        }
        __syncthreads();
    }

    // epilogue regs
    float4 bd = *(const float4*)&b_dt[n0 + tx * 4];
    float4 dp4 = *(const float4*)&Dp[n0 + tx * 4];
    float bda[4] = {bd.x, bd.y, bd.z, bd.w};
    float dpa[4] = {dp4.x, dp4.y, dp4.z, dp4.w};
    float2 d2[4][4];
    unsigned int su[4][4];
#pragma unroll
    for (int i = 0; i < 4; ++i) {
        int bl = m0 + ty * 4 + i;
        ushort4 u4 = *(const ushort4*)&ub[(size_t)bl * DI_ + n0 + tx * 4];
        ushort4 s4 = *(const ushort4*)&szb[(size_t)bl * DI_ + n0 + tx * 4];
        unsigned short ua[4] = {u4.x, u4.y, u4.z, u4.w};
        unsigned short sa[4] = {s4.x, s4.y, s4.z, s4.w};
#pragma unroll
        for (int j = 0; j < 4; ++j) {
            float v = acc[i][j] + bda[j];
            float dtv = fmaxf(v, 0.f) + __logf(1.f + __expf(-fabsf(v)));
            float uu = bf2f(ua[j]);
            float szv = bf2f(sa[j]);
            d2[i][j] = make_float2(dtv, dtv * uu);
            su[i][j] = ((unsigned)f2bf(uu * dpa[j] * szv) << 16) | (unsigned)f2bf(szv);
        }
    }

    // pass 1: {dt, dtu} transpose through LDS
#pragma unroll
    for (int i = 0; i < 4; ++i)
#pragma unroll
        for (int j = 0; j < 4; ++j)
            T2[ty * 4 + i][tx * 4 + j] = d2[i][j];
    __syncthreads();
#pragma unroll
    for (int i = 0; i < 8; ++i) {
        int c_l = (tid >> 5) + i * 8;
#pragma unroll
        for (int jj = 0; jj < 2; ++jj) {
            int bl_l = (tid & 31) + jj * 32;
            dtduT[(size_t)(n0 + c_l) * BL_ + m0 + bl_l] = T2[bl_l][c_l];
        }
    }
    __syncthreads();

    // pass 2: szd transpose through LDS
#pragma unroll
    for (int i = 0; i < 4; ++i)
#pragma unroll
        for (int j = 0; j < 4; ++j)
            TU[ty * 4 + i][tx * 4 + j] = su[i][j];
    __syncthreads();
#pragma unroll
    for (int i = 0; i < 8; ++i) {
        int c_l = (tid >> 5) + i * 8;
#pragma unroll
        for (int jj = 0; jj < 2; ++jj) {
            int bl_l = (tid & 31) + jj * 32;
            szdT[(size_t)(n0 + c_l) * BL_ + m0 + bl_l] = TU[bl_l][c_l];
        }
    }
}

// ---------------- Scan v5: 2 channels/block, direct proj B/C, DPP reduce ----------------
__global__ __launch_bounds__(256) void scan_v5(
        const float2* __restrict__ dtduT, const unsigned int* __restrict__ szdT,
        const float* __restrict__ proj, const float* __restrict__ A_log,
        unsigned short* __restrict__ yzT) {
    int bc = blockIdx.x;            // 0..2047
    int b = bc >> 10;
    int cp = bc & 1023;
    int t = threadIdx.x;
    int n = t & 15;
    int cs = (t >> 4) & 1;
    int chunk = t >> 5;             // 0..7, 128 l each
    int c = cp * 2 + cs;

    __shared__ float dd[2][(L_ + 32) * 2];   // {dt,dtu}, +2 float2 pad per 64 l
    __shared__ float sA[8][32];
    __shared__ float sB[8][32];
    __shared__ float ps[2][L_ + 64];

    {   // stage both channel streams, coalesced
        int half = t >> 7;
        int tt = t & 127;
        int l = tt * 8;
        int cload = cp * 2 + half;
        const float4* g = (const float4*)(dtduT + (size_t)cload * BL_ + (size_t)b * L_ + l);
        int il2 = l + ((l >> 6) << 1);
        float* dst = &dd[half][il2 * 2];
        *(float4*)(dst + 0)  = g[0];
        *(float4*)(dst + 4)  = g[1];
        *(float4*)(dst + 8)  = g[2];
        *(float4*)(dst + 12) = g[3];
    }
    __syncthreads();

    float A = -__expf(A_log[c * N_ + n]);
    int l0 = chunk * 128;
    const float* pB = proj + (size_t)b * L_ * 96 + R_ + n;
    const float* pC = pB + N_;

    // Phase 1: chunk-local scan over 128 l
    float a = 1.f, acc = 0.f;
#pragma unroll
    for (int h = 0; h < 2; ++h) {
        int lb = l0 + h * 64;
        const float* ddp = &dd[cs][(lb + ((lb >> 6) << 1)) * 2];
        const float* pBb = pB + (size_t)lb * 96;
#pragma unroll
        for (int q = 0; q < 16; ++q) {
            float4 d0 = *(const float4*)(ddp + q * 8);
            float4 d1 = *(const float4*)(ddp + q * 8 + 4);
            float b0 = pBb[(q*4 + 0) * 96];
            float b1 = pBb[(q*4 + 1) * 96];
            float b2 = pBb[(q*4 + 2) * 96];
            float b3 = pBb[(q*4 + 3) * 96];
            float e;
            e = __expf(d0.x * A); a *= e; acc = fmaf(e, acc, d0.y * b0);
            e = __expf(d0.z * A); a *= e; acc = fmaf(e, acc, d0.w * b1);
            e = __expf(d1.x * A); a *= e; acc = fmaf(e, acc, d1.y * b2);
            e = __expf(d1.z * A); a *= e; acc = fmaf(e, acc, d1.w * b3);
        }
    }
    sA[chunk][t & 31] = a;
    sB[chunk][t & 31] = acc;
    __syncthreads();

    // Phase 2: serial combine across 8 chunks (32 threads: one per (cs,n))
    if (t < 32) {
        float hc = 0.f;
#pragma unroll
        for (int j = 0; j < 8; ++j) {
            float aj = sA[j][t];
            float bj = sB[j][t];
            sB[j][t] = hc;
            hc = fmaf(aj, hc, bj);
        }
    }
    __syncthreads();
    float h = sB[chunk][t & 31];

    // Phase 3: re-walk; DPP row-sum -> lane n==15 of each 16-lane group
#pragma unroll
    for (int hh = 0; hh < 2; ++hh) {
        int lb = l0 + hh * 64;
        const float* ddp = &dd[cs][(lb + ((lb >> 6) << 1)) * 2];
        const float* pBb = pB + (size_t)lb * 96;
        const float* pCb = pC + (size_t)lb * 96;
        float* psb = &ps[cs][IDX4(lb)];
#pragma unroll
        for (int q = 0; q < 16; ++q) {
            float4 d0 = *(const float4*)(ddp + q * 8);
            float4 d1 = *(const float4*)(ddp + q * 8 + 4);
            float b0 = pBb[(q*4 + 0) * 96], c0 = pCb[(q*4 + 0) * 96];
            float b1 = pBb[(q*4 + 1) * 96], c1 = pCb[(q*4 + 1) * 96];
            float b2 = pBb[(q*4 + 2) * 96], c2 = pCb[(q*4 + 2) * 96];
            float b3 = pBb[(q*4 + 3) * 96], c3 = pCb[(q*4 + 3) * 96];
            float e, p0, p1, p2, p3;
            e = __expf(d0.x * A); h = fmaf(e, h, d0.y * b0); p0 = row16_sum(h * c0);
            e = __expf(d0.z * A); h = fmaf(e, h, d0.w * b1); p1 = row16_sum(h * c1);
            e = __expf(d1.x * A); h = fmaf(e, h, d1.y * b2); p2 = row16_sum(h * c2);
            e = __expf(d1.z * A); h = fmaf(e, h, d1.w * b3); p3 = row16_sum(h * c3);
            if (n == 15) *(float4*)&psb[q * 4] = (float4){p0, p1, p2, p3};
        }
    }
    __syncthreads();

    // Epilogue: y = p * sz + u*D*sz, 8 per thread, coalesced
    {
        int half = t >> 7;
        int tt = t & 127;
        int l = tt * 8;
        int c_out = cp * 2 + half;
        size_t tb = (size_t)c_out * BL_ + (size_t)b * L_;
        const float* pp = &ps[half][IDX4(l)];
        ushort4 o[2];
#pragma unroll
        for (int g = 0; g < 2; ++g) {
            float4 p4 = *(const float4*)(pp + g * 4);
            uint4 sd4 = *(const uint4*)(szdT + tb + l + g * 4);
            o[g].x = f2bf(p4.x * bf2f((unsigned short)(sd4.x & 0xffff)) + bf2f((unsigned short)(sd4.x >> 16)));
            o[g].y = f2bf(p4.y * bf2f((unsigned short)(sd4.y & 0xffff)) + bf2f((unsigned short)(sd4.y >> 16)));
            o[g].z = f2bf(p4.z * bf2f((unsigned short)(sd4.z & 0xffff)) + bf2f((unsigned short)(sd4.z >> 16)));
            o[g].w = f2bf(p4.w * bf2f((unsigned short)(sd4.w & 0xffff)) + bf2f((unsigned short)(sd4.w >> 16)));
        }
        *(ushort4*)(yzT + tb + l) = o[0];
        *(ushort4*)(yzT + tb + l + 4) = o[1];
    }
}

// ---------------- Transpose back: yzT (DI x BL) -> yzb (BL x DI) ----------------
__global__ void transpose_y(const unsigned short* __restrict__ yzT, unsigned short* __restrict__ yz) {
    __shared__ unsigned short t[32][33];
    int c0 = blockIdx.y * 32, bl0 = blockIdx.x * 32;
    int r = threadIdx.x >> 5;
    int col = threadIdx.x & 31;
#pragma unroll
    for (int i = 0; i < 4; ++i)
        t[r + i*8][col] = yzT[(size_t)(c0 + r + i*8) * BL_ + bl0 + col];
    __syncthreads();
#pragma unroll
    for (int i = 0; i < 4; ++i)
        yz[(size_t)(bl0 + r + i*8) * DI_ + c0 + col] = t[col][r + i*8];
}

extern "C" void kernel_launch(void* const* d_in, const int* in_sizes, int n_in,
                              void* d_out, int out_size, void* d_ws, size_t ws_size,
                              hipStream_t stream) {
    const float* x       = (const float*)d_in[0];
    const float* ln_w    = (const float*)d_in[1];
    const float* ln_b    = (const float*)d_in[2];
    const float* W_in    = (const float*)d_in[3];
    const float* conv_w  = (const float*)d_in[4];
    const float* conv_b  = (const float*)d_in[5];
    const float* W_x     = (const float*)d_in[6];
    const float* W_dt    = (const float*)d_in[7];
    const float* b_dt    = (const float*)d_in[8];
    const float* A_log   = (const float*)d_in[9];
    const float* D_param = (const float*)d_in[10];
    const float* W_out   = (const float*)d_in[11];
    float* out = (float*)d_out;

    uint8_t* p = (uint8_t*)d_ws;
    unsigned short* hb    = (unsigned short*)p;  p += (size_t)BL_ * D_ * 2;          // 4 MB  (dead after GEMM2)
    unsigned short* WinT  = (unsigned short*)p;  p += (size_t)4096 * 1024 * 2;       // 8 MB  (dead after GEMM2)
    float*          xib   = (float*)p;           p += (size_t)BL_ * DI_ * 4;         // 16 MB
    unsigned short* szb   = (unsigned short*)p;  p += (size_t)BL_ * DI_ * 2;         // 8 MB
    unsigned short* ub    = (unsigned short*)p;  p += (size_t)BL_ * DI_ * 2;         // 8 MB
    unsigned short* WxT   = (unsigned short*)p;  p += (size_t)96 * DI_ * 2;          // 0.375 MB
    float*          proj  = (float*)p;           p += (size_t)BL_ * 96 * 4;          // 0.75 MB
    unsigned short* WoutT = (unsigned short*)p;  p += (size_t)1024 * DI_ * 2;        // 4 MB
    float2*         dtduT = (float2*)p;          p += (size_t)BL_ * DI_ * 8;         // 32 MB
    unsigned int*   szdT  = (unsigned int*)p;    p += (size_t)BL_ * DI_ * 4;         // 16 MB
    unsigned short* yzT   = (unsigned short*)p;  p += (size_t)BL_ * DI_ * 2;         // 8 MB
    // yzb aliases the dead hb+WinT region (8 MB <= 12 MB; written after GEMM2 done)
    unsigned short* yzb   = (unsigned short*)d_ws;

    hipMemsetAsync(proj, 0, (size_t)BL_ * 96 * 4, stream);
    hipMemcpyAsync(out, x, (size_t)BL_ * D_ * 4, hipMemcpyDeviceToDevice, stream);

    // weight transposes (one dispatch)
    transpose_cast_all<<<6336, 256, 0, stream>>>(W_in, W_x, W_out, WinT, WxT, WoutT);

    // 1. LayerNorm -> bf16
    ln_kernel<<<BL_, 256, 0, stream>>>(x, ln_w, ln_b, hb);

    // 2. xz = h @ W_in  (MFMA; epilogue splits xi fp32 / silu(z) bf16)
    mfma_gemm_bt<128, 3><<<dim3(4096 / 128, BL_ / 128, 1), 256, 0, stream>>>(
        hb, 1024, WinT, 1024, nullptr, 0, 1024, xib, szb);

    // 3. u = silu(conv(xi)) -> bf16
    conv_silu_kernel<<<(BL_ * DI_) / 256, 256, 0, stream>>>(xib, conv_w, conv_b, ub);

    // 4. proj += u @ W_x  (MFMA, split-K=16 atomic)
    mfma_gemm_bt<96, 1><<<dim3(1, BL_ / 128, 16), 256, 0, stream>>>(
        ub, DI_, WxT, DI_, proj, 96, 128, nullptr, nullptr);

    // 5. fused dt-GEMM + softplus + pack + transpose
    dtprep<<<dim3(DI_ / 64, BL_ / 64), 256, 0, stream>>>(
        proj, W_dt, b_dt, ub, szb, D_param, dtduT, szdT);

    // 6. scan v5 (2 channels/block) -> yzT
    scan_v5<<<B_ * DI_ / 2, 256, 0, stream>>>(dtduT, szdT, proj, A_log, yzT);

    // 6b. yzT -> row-major yzb
    transpose_y<<<dim3(BL_ / 32, DI_ / 32), 256, 0, stream>>>(yzT, yzb);

    // 7. out += yz @ W_out  (MFMA, split-K=2 atomic onto residual)
    mfma_gemm_bt<128, 1><<<dim3(1024 / 128, BL_ / 128, 2), 256, 0, stream>>>(
        yzb, DI_, WoutT, DI_, out, 1024, 1024, nullptr, nullptr);
}